// Round 8
// baseline (376.660 us; speedup 1.0000x reference)
//
#include <hip/hip_runtime.h>
#include <hip/hip_fp16.h>

#define D 64
#define EPS 1e-5f

// CSR bucketing params: buckets of 512 consecutive dst nodes
#define BK_SHIFT 9
#define BK_W 512
#define NBMAX 256        // supports n up to 131072
#define BK_CAP 8192      // avg 6144 edges/bucket, +26 sigma margin
#define CHUNK 4096       // edges per bucket_k block

// ---------------- Phase A: bucketize edges; pack (src<<9 | dst_local) ----------------

__global__ __launch_bounds__(256) void bucket_k(const int* __restrict__ src,
                                                const int* __restrict__ dst,
                                                int* __restrict__ bcnt,
                                                int* __restrict__ pairs,
                                                int e, int nbk) {
  __shared__ int hcnt[NBMAX];
  __shared__ int hbase[NBMAX];
  const int t = threadIdx.x;
  const int e0 = blockIdx.x * CHUNK;
  const int e1 = min(e0 + CHUNK, e);
  for (int i = t; i < nbk; i += 256) hcnt[i] = 0;
  __syncthreads();
  for (int i = e0 + t; i < e1; i += 256)
    atomicAdd(&hcnt[dst[i] >> BK_SHIFT], 1);
  __syncthreads();
  for (int i = t; i < nbk; i += 256) {
    int c = hcnt[i];
    hbase[i] = c ? atomicAdd(&bcnt[i], c) : 0;
    hcnt[i] = 0;   // reuse as cursor
  }
  __syncthreads();
  for (int i = e0 + t; i < e1; i += 256) {
    int s = src[i], d = dst[i];
    int b = d >> BK_SHIFT;
    int r = hbase[b] + atomicAdd(&hcnt[b], 1);
    if (r < BK_CAP) pairs[(size_t)b * BK_CAP + r] = (s << BK_SHIFT) | (d & (BK_W - 1));
  }
}

// ---------------- Fused CSR: per-bucket hist -> scan -> rpdeg/dis -> place -> col ----
// col lives in padded slabs (bucket b at b*BK_CAP); rpdeg[node] = (start, deg).

__global__ __launch_bounds__(256) void bucket2csr_k(const int* __restrict__ bcnt,
                                                    const int* __restrict__ pairs,
                                                    int2* __restrict__ rpdeg,
                                                    float* __restrict__ dis,
                                                    int* __restrict__ col, int n) {
  __shared__ int h[BK_W];
  __shared__ int cur[BK_W];
  __shared__ int s1[256], s2[256];
  __shared__ int stage[BK_CAP];
  const int b = blockIdx.x, t = threadIdx.x;
  const int base = b << BK_SHIFT;
  const int slab0 = b * BK_CAP;
  const int m = min(bcnt[b], BK_CAP);

  h[t] = 0; h[t + 256] = 0;
  __syncthreads();
  const int* p = pairs + (size_t)b * BK_CAP;
  for (int i = t; i < m; i += 256) atomicAdd(&h[p[i] & (BK_W - 1)], 1);
  __syncthreads();

  s1[t] = h[t]; s2[t] = h[t + 256];
  __syncthreads();
  for (int off = 1; off < 256; off <<= 1) {
    int x1 = (t >= off) ? s1[t - off] : 0;
    int x2 = (t >= off) ? s2[t - off] : 0;
    __syncthreads();
    s1[t] += x1; s2[t] += x2;
    __syncthreads();
  }
  const int tot1 = s1[255];
  cur[t]       = s1[t] - h[t];
  cur[t + 256] = tot1 + s2[t] - h[t + 256];
  {
    int n1 = base + t, n2 = base + t + 256;
    if (n1 < n) { rpdeg[n1] = make_int2(slab0 + cur[t], h[t]);
                  dis[n1] = rsqrtf((float)h[t] + 1.0f); }
    if (n2 < n) { rpdeg[n2] = make_int2(slab0 + cur[t + 256], h[t + 256]);
                  dis[n2] = rsqrtf((float)h[t + 256] + 1.0f); }
  }
  __syncthreads();

  for (int i = t; i < m; i += 256) {
    int pk = p[i];
    int r = atomicAdd(&cur[pk & (BK_W - 1)], 1);
    stage[r] = pk >> BK_SHIFT;
  }
  __syncthreads();
  for (int i = t; i < m; i += 256) col[slab0 + i] = stage[i];
}

// ---------------- BN/bias folding ----------------

__global__ void bnprep_k(const float* __restrict__ b1, const float* __restrict__ b2,
                         const float* __restrict__ b3,
                         const float* __restrict__ g1, const float* __restrict__ be1,
                         const float* __restrict__ rm1, const float* __restrict__ rv1,
                         const float* __restrict__ g2, const float* __restrict__ be2,
                         const float* __restrict__ rm2, const float* __restrict__ rv2,
                         float* __restrict__ scsh) {
  int t = threadIdx.x;
  int j = t & 63, l = t >> 6;
  float sc, sh;
  if (l == 0)      { sc = g1[j] * rsqrtf(rv1[j] + EPS); sh = (b1[j] - rm1[j]) * sc + be1[j]; }
  else if (l == 1) { sc = g2[j] * rsqrtf(rv2[j] + EPS); sh = (b2[j] - rm2[j]) * sc + be2[j]; }
  else             { sc = 1.0f;                          sh = b3[j]; }
  scsh[l * 128 + j] = sc;
  scsh[l * 128 + 64 + j] = sh;
}

// ---------------- GEMM: out[r] = dis[r] * (in[r] @ W), fp16 out, fp32/fp16 in --------

#define GT_R 128
#define XT_LD 132

__device__ inline float ld1(const float* p)  { return *p; }
__device__ inline float ld1(const __half* p) { return __half2float(*p); }

template <typename InT>
__global__ __launch_bounds__(256) void gemm_k(const InT* __restrict__ in,
                                              const float* __restrict__ W,
                                              const float* __restrict__ dis,
                                              __half* __restrict__ out, int nrows) {
  __shared__ float ws[64 * 64];
  __shared__ float xt[64 * XT_LD];
  __shared__ float dtile[GT_R];

  const int t    = threadIdx.x;
  const int lane = t & 63;
  const int w    = t >> 6;
  const int row0 = blockIdx.x * GT_R;

  for (int i = t; i < 1024; i += 256)
    ((float4*)ws)[i] = ((const float4*)W)[i];

  if (t < GT_R) {
    int r = row0 + t;
    dtile[t] = (r < nrows) ? dis[r] : 0.f;
  }

#pragma unroll
  for (int j = 0; j < 8; ++j) {
    int Q = w + 4 * j;
    int r = row0 + 4 * Q;
    float4 v;
    v.x = (r + 0 < nrows) ? ld1(&in[(size_t)(r + 0) * D + lane]) : 0.f;
    v.y = (r + 1 < nrows) ? ld1(&in[(size_t)(r + 1) * D + lane]) : 0.f;
    v.z = (r + 2 < nrows) ? ld1(&in[(size_t)(r + 2) * D + lane]) : 0.f;
    v.w = (r + 3 < nrows) ? ld1(&in[(size_t)(r + 3) * D + lane]) : 0.f;
    *(float4*)&xt[lane * XT_LD + 4 * Q] = v;
  }
  __syncthreads();

  const int cq = (t & 15) * 4;
  const int rg = (t >> 4) * 8;
  float acc[8][4] = {};

#pragma unroll 4
  for (int k = 0; k < 64; ++k) {
    float4 b   = *(const float4*)&ws[k * 64 + cq];
    float4 alo = *(const float4*)&xt[k * XT_LD + rg];
    float4 ahi = *(const float4*)&xt[k * XT_LD + rg + 4];
    const float ar[8] = {alo.x, alo.y, alo.z, alo.w, ahi.x, ahi.y, ahi.z, ahi.w};
#pragma unroll
    for (int i = 0; i < 8; ++i) {
      acc[i][0] = fmaf(ar[i], b.x, acc[i][0]);
      acc[i][1] = fmaf(ar[i], b.y, acc[i][1]);
      acc[i][2] = fmaf(ar[i], b.z, acc[i][2]);
      acc[i][3] = fmaf(ar[i], b.w, acc[i][3]);
    }
  }

#pragma unroll
  for (int i = 0; i < 8; ++i) {
    int r = row0 + rg + i;
    if (r < nrows) {
      float dsc = dtile[rg + i];
      union { __half2 h[2]; float2 f; } u;
      u.h[0] = __floats2half2_rn(dsc * acc[i][0], dsc * acc[i][1]);
      u.h[1] = __floats2half2_rn(dsc * acc[i][2], dsc * acc[i][3]);
      *(float2*)&out[(size_t)r * D + cq] = u.f;
    }
  }
}

// ---------------- Aggregation: 4 src rows per gather instruction ----------------
// Wave = 1 dst node. Lane = (rowsel = lane>>4, sl = lane&15): 16-lane group
// rowsel covers edge e+rowsel; lane loads uint2 = 4 fp16 feats (4sl..4sl+3).
// One gather instruction = 512 B (4 rows). Epilogue: shfl_xor(16,32) reduce.

template <bool RELU, typename OutT>
__global__ __launch_bounds__(256) void agg_k(const __half* __restrict__ h2s,
                                             const int2* __restrict__ rpdeg,
                                             const int* __restrict__ col,
                                             const float* __restrict__ dis,
                                             const float* __restrict__ scsh,
                                             OutT* __restrict__ out, int n) {
  const int lane   = threadIdx.x & 63;
  const int node   = __builtin_amdgcn_readfirstlane((blockIdx.x * blockDim.x + threadIdx.x) >> 6);
  if (node >= n) return;
  const int rowsel = lane >> 4;
  const int sl     = lane & 15;
  const uint2* __restrict__ h2v = (const uint2*)h2s;   // row = 16 x uint2

  const int2 rd = rpdeg[node];
  const int p0 = rd.x, deg = rd.y;

  float a0 = 0.f, a1 = 0.f, a2 = 0.f, a3 = 0.f;   // acc set A (+self)
  float b0 = 0.f, b1 = 0.f, b2 = 0.f, b3 = 0.f;   // acc set B
  float c0 = 0.f, c1 = 0.f, c2 = 0.f, c3 = 0.f;   // acc set C
  float d0 = 0.f, d1 = 0.f, d2 = 0.f, d3 = 0.f;   // acc set D

  {  // self-loop term: added by rowsel group 0 only
    uint2 r = h2v[(size_t)node * 16 + sl];
    float2 f0 = __half22float2(*(__half2*)&r.x);
    float2 f1 = __half22float2(*(__half2*)&r.y);
    if (rowsel == 0) { a0 = f0.x; a1 = f0.y; a2 = f1.x; a3 = f1.y; }
  }

  const int last = p0 + deg - 1;
  for (int e = 0; e < deg; e += 16) {
    const int j0 = e + rowsel, j1 = j0 + 4, j2 = j0 + 8, j3 = j0 + 12;
    const int s0 = col[min(p0 + j0, last)];
    const int s1 = col[min(p0 + j1, last)];
    const int s2 = col[min(p0 + j2, last)];
    const int s3 = col[min(p0 + j3, last)];
    const uint2 r0 = h2v[(size_t)s0 * 16 + sl];
    const uint2 r1 = h2v[(size_t)s1 * 16 + sl];
    const uint2 r2 = h2v[(size_t)s2 * 16 + sl];
    const uint2 r3 = h2v[(size_t)s3 * 16 + sl];
    {
      float2 f0 = __half22float2(*(__half2*)&r0.x);
      float2 f1 = __half22float2(*(__half2*)&r0.y);
      if (j0 < deg) { a0 += f0.x; a1 += f0.y; a2 += f1.x; a3 += f1.y; }
    }
    {
      float2 f0 = __half22float2(*(__half2*)&r1.x);
      float2 f1 = __half22float2(*(__half2*)&r1.y);
      if (j1 < deg) { b0 += f0.x; b1 += f0.y; b2 += f1.x; b3 += f1.y; }
    }
    {
      float2 f0 = __half22float2(*(__half2*)&r2.x);
      float2 f1 = __half22float2(*(__half2*)&r2.y);
      if (j2 < deg) { c0 += f0.x; c1 += f0.y; c2 += f1.x; c3 += f1.y; }
    }
    {
      float2 f0 = __half22float2(*(__half2*)&r3.x);
      float2 f1 = __half22float2(*(__half2*)&r3.y);
      if (j3 < deg) { d0 += f0.x; d1 += f0.y; d2 += f1.x; d3 += f1.y; }
    }
  }

  float r0 = (a0 + b0) + (c0 + d0);
  float r1 = (a1 + b1) + (c1 + d1);
  float r2 = (a2 + b2) + (c2 + d2);
  float r3 = (a3 + b3) + (c3 + d3);
  // reduce across the 4 rowsel groups (lanes sl, sl+16, sl+32, sl+48)
  r0 += __shfl_xor(r0, 16, 64); r1 += __shfl_xor(r1, 16, 64);
  r2 += __shfl_xor(r2, 16, 64); r3 += __shfl_xor(r3, 16, 64);
  r0 += __shfl_xor(r0, 32, 64); r1 += __shfl_xor(r1, 32, 64);
  r2 += __shfl_xor(r2, 32, 64); r3 += __shfl_xor(r3, 32, 64);

  const float di = dis[node];
  const float4 sc = *(const float4*)&scsh[4 * sl];
  const float4 sh = *(const float4*)&scsh[64 + 4 * sl];
  float o0 = fmaf(di * r0, sc.x, sh.x);
  float o1 = fmaf(di * r1, sc.y, sh.y);
  float o2 = fmaf(di * r2, sc.z, sh.z);
  float o3 = fmaf(di * r3, sc.w, sh.w);
  if (RELU) {
    o0 = fmaxf(o0, 0.f); o1 = fmaxf(o1, 0.f);
    o2 = fmaxf(o2, 0.f); o3 = fmaxf(o3, 0.f);
  }
  if (rowsel == 0) {
    if constexpr (sizeof(OutT) == 2) {
      union { __half2 h[2]; uint2 u; } v;
      v.h[0] = __floats2half2_rn(o0, o1);
      v.h[1] = __floats2half2_rn(o2, o3);
      *(uint2*)&out[(size_t)node * D + 4 * sl] = v.u;
    } else {
      *(float4*)&out[(size_t)node * D + 4 * sl] = make_float4(o0, o1, o2, o3);
    }
  }
}

// ---------------- Global mean pool (batch is sorted) ----------------

__global__ __launch_bounds__(256) void pool_k(const float* __restrict__ h,
                                              const int* __restrict__ batch,
                                              float* __restrict__ psum,
                                              float* __restrict__ pcnt, int n) {
  int lane  = threadIdx.x & 63;
  int wid   = __builtin_amdgcn_readfirstlane((blockIdx.x * blockDim.x + threadIdx.x) >> 6);
  int start = wid * 64;
  if (start >= n) return;
  int end = min(start + 64, n);
  int cur = batch[start];
  float sum = 0.f;
  int run = 0;
  for (int i = start; i < end; ++i) {
    int g = batch[i];
    if (g != cur) {
      atomicAdd(&psum[cur * D + lane], sum);
      if (lane == 0) atomicAdd(&pcnt[cur], (float)run);
      sum = 0.f; run = 0; cur = g;
    }
    sum += h[(size_t)i * D + lane];
    run += 1;
  }
  atomicAdd(&psum[cur * D + lane], sum);
  if (lane == 0) atomicAdd(&pcnt[cur], (float)run);
}

__global__ void pooldiv_k(const float* __restrict__ psum, const float* __restrict__ pcnt,
                          float* __restrict__ hg) {
  int t = blockIdx.x * blockDim.x + threadIdx.x;
  if (t < 64 * D) hg[t] = psum[t] / fmaxf(pcnt[t >> 6], 1.0f);
}

// ---------------- launcher ----------------

extern "C" void kernel_launch(void* const* d_in, const int* in_sizes, int n_in,
                              void* d_out, int out_size, void* d_ws, size_t ws_size,
                              hipStream_t stream) {
  const float* x   = (const float*)d_in[0];
  const int*   ei  = (const int*)d_in[1];
  const int*   bat = (const int*)d_in[2];
  const float* W1  = (const float*)d_in[3];
  const float* W2  = (const float*)d_in[4];
  const float* W3  = (const float*)d_in[5];
  const float* b1  = (const float*)d_in[6];
  const float* b2  = (const float*)d_in[7];
  const float* b3  = (const float*)d_in[8];
  const float* g1  = (const float*)d_in[9];
  const float* be1 = (const float*)d_in[10];
  const float* rm1 = (const float*)d_in[11];
  const float* rv1 = (const float*)d_in[12];
  const float* g2  = (const float*)d_in[13];
  const float* be2 = (const float*)d_in[14];
  const float* rm2 = (const float*)d_in[15];
  const float* rv2 = (const float*)d_in[16];

  const int n = in_sizes[0] / D;   // 100000
  const int e = in_sizes[1] / 2;   // 1200000
  const int* src = ei;
  const int* dst = ei + e;
  const int nbk = (n + BK_W - 1) >> BK_SHIFT;   // 196

  char* ws = (char*)d_ws;
  size_t off = 0;
  auto alloc = [&](size_t bytes) -> void* {
    void* p = ws + off;
    off = (off + bytes + 255) & ~(size_t)255;
    return p;
  };
  __half* buf16 = (__half*)alloc((size_t)n * D * 2);        // agg fp16 out (layers 1,2)
  int*    pairs = (int*)alloc((size_t)NBMAX * BK_CAP * 4);  // bucket slabs
  __half* hbuf  = (__half*)alloc((size_t)n * D * 2);        // gemm fp16 out (dis-scaled)
  int2*   rpdeg = (int2*)alloc((size_t)n * 8);
  float*  dis   = (float*)alloc((size_t)n * 4);
  int*    col   = (int*)alloc((size_t)NBMAX * BK_CAP * 4);  // CSR in padded slabs
  float*  scsh  = (float*)alloc(6 * 64 * 4);
  // zero-init cluster: bcnt + psum + pcnt in one contiguous memset
  int*    bcnt  = (int*)alloc(NBMAX * 4);
  float*  psum  = (float*)alloc(64 * D * 4);
  float*  pcnt  = (float*)alloc(64 * 4);
  const size_t zbytes = ((char*)pcnt + 64 * 4) - (char*)bcnt;

  float* hout = (float*)d_out;
  float* hg   = (float*)d_out + (size_t)n * D;

  hipMemsetAsync(bcnt, 0, zbytes, stream);

  bucket_k<<<(e + CHUNK - 1) / CHUNK, 256, 0, stream>>>(src, dst, bcnt, pairs, e, nbk);
  bucket2csr_k<<<nbk, 256, 0, stream>>>(bcnt, pairs, rpdeg, dis, col, n);
  bnprep_k<<<1, 192, 0, stream>>>(b1, b2, b3, g1, be1, rm1, rv1, g2, be2, rm2, rv2, scsh);

  const int gemm_blocks = (n + GT_R - 1) / GT_R;
  const int agg_blocks  = (n * 64 + 255) / 256;

  // layer 1
  gemm_k<float><<<gemm_blocks, 256, 0, stream>>>(x, W1, dis, hbuf, n);
  agg_k<true, __half><<<agg_blocks, 256, 0, stream>>>(hbuf, rpdeg, col, dis, scsh + 0 * 128, buf16, n);
  // layer 2
  gemm_k<__half><<<gemm_blocks, 256, 0, stream>>>(buf16, W2, dis, hbuf, n);
  agg_k<true, __half><<<agg_blocks, 256, 0, stream>>>(hbuf, rpdeg, col, dis, scsh + 1 * 128, buf16, n);
  // layer 3
  gemm_k<__half><<<gemm_blocks, 256, 0, stream>>>(buf16, W3, dis, hbuf, n);
  agg_k<false, float><<<agg_blocks, 256, 0, stream>>>(hbuf, rpdeg, col, dis, scsh + 2 * 128, hout, n);

  // pooling
  const int pool_waves = (n + 63) / 64;
  pool_k<<<(pool_waves * 64 + 255) / 256, 256, 0, stream>>>(hout, bat, psum, pcnt, n);
  pooldiv_k<<<(64 * D + 255) / 256, 256, 0, stream>>>(psum, pcnt, hg);
}

// Round 9
// 365.427 us; speedup vs baseline: 1.0307x; 1.0307x over previous
//
#include <hip/hip_runtime.h>
#include <hip/hip_fp16.h>

#define D 64
#define EPS 1e-5f

// CSR bucketing params: buckets of 512 consecutive dst nodes
#define BK_SHIFT 9
#define BK_W 512
#define NBMAX 256        // supports n up to 131072
#define BK_CAP 8192      // avg padded ~7040/bucket; margin ok
#define CHUNK 4096       // edges per bucket_k block

// ---------------- Phase A: bucketize edges; pack (src<<9 | dst_local) ----------------

__global__ __launch_bounds__(256) void bucket_k(const int* __restrict__ src,
                                                const int* __restrict__ dst,
                                                int* __restrict__ bcnt,
                                                int* __restrict__ pairs,
                                                int e, int nbk) {
  __shared__ int hcnt[NBMAX];
  __shared__ int hbase[NBMAX];
  const int t = threadIdx.x;
  const int e0 = blockIdx.x * CHUNK;
  const int e1 = min(e0 + CHUNK, e);
  for (int i = t; i < nbk; i += 256) hcnt[i] = 0;
  __syncthreads();
  for (int i = e0 + t; i < e1; i += 256)
    atomicAdd(&hcnt[dst[i] >> BK_SHIFT], 1);
  __syncthreads();
  for (int i = t; i < nbk; i += 256) {
    int c = hcnt[i];
    hbase[i] = c ? atomicAdd(&bcnt[i], c) : 0;
    hcnt[i] = 0;   // reuse as cursor
  }
  __syncthreads();
  for (int i = e0 + t; i < e1; i += 256) {
    int s = src[i], d = dst[i];
    int b = d >> BK_SHIFT;
    int r = hbase[b] + atomicAdd(&hcnt[b], 1);
    if (r < BK_CAP) pairs[(size_t)b * BK_CAP + r] = (s << BK_SHIFT) | (d & (BK_W - 1));
  }
}

// ---------------- Fused CSR: hist -> padded scan -> rpdeg/dis -> place -> col --------
// Node segments padded to multiples of 4 ints (so agg can int4-load indices).
// stage pre-zeroed => pad slots hold index 0 (valid row; data zeroed by predicate).

__global__ __launch_bounds__(256) void bucket2csr_k(const int* __restrict__ bcnt,
                                                    const int* __restrict__ pairs,
                                                    int2* __restrict__ rpdeg,
                                                    float* __restrict__ dis,
                                                    int* __restrict__ col, int n) {
  __shared__ int h[BK_W];
  __shared__ int cur[BK_W];
  __shared__ int s1[256], s2[256];
  __shared__ int stage[BK_CAP];
  const int b = blockIdx.x, t = threadIdx.x;
  const int base = b << BK_SHIFT;
  const int slab0 = b * BK_CAP;
  const int m = min(bcnt[b], BK_CAP);

  h[t] = 0; h[t + 256] = 0;
  for (int i = t; i < BK_CAP; i += 256) stage[i] = 0;
  __syncthreads();
  const int* p = pairs + (size_t)b * BK_CAP;
  for (int i = t; i < m; i += 256) atomicAdd(&h[p[i] & (BK_W - 1)], 1);
  __syncthreads();

  const int pc1 = (h[t] + 3) & ~3;         // padded counts (x4 alignment)
  const int pc2 = (h[t + 256] + 3) & ~3;
  s1[t] = pc1; s2[t] = pc2;
  __syncthreads();
  for (int off = 1; off < 256; off <<= 1) {
    int x1 = (t >= off) ? s1[t - off] : 0;
    int x2 = (t >= off) ? s2[t - off] : 0;
    __syncthreads();
    s1[t] += x1; s2[t] += x2;
    __syncthreads();
  }
  const int tot1 = s1[255];
  const int mpad = tot1 + s2[255];
  cur[t]       = s1[t] - pc1;
  cur[t + 256] = tot1 + s2[t] - pc2;
  {
    int n1 = base + t, n2 = base + t + 256;
    if (n1 < n) { rpdeg[n1] = make_int2(slab0 + cur[t], h[t]);
                  dis[n1] = rsqrtf((float)h[t] + 1.0f); }
    if (n2 < n) { rpdeg[n2] = make_int2(slab0 + cur[t + 256], h[t + 256]);
                  dis[n2] = rsqrtf((float)h[t + 256] + 1.0f); }
  }
  __syncthreads();

  for (int i = t; i < m; i += 256) {
    int pk = p[i];
    int r = atomicAdd(&cur[pk & (BK_W - 1)], 1);
    stage[r] = pk >> BK_SHIFT;
  }
  __syncthreads();
  const int mout = min(mpad + 16, BK_CAP);   // +16 zero tail for agg over-read
  for (int i = t; i < mout; i += 256) col[slab0 + i] = stage[i];
}

// ---------------- BN/bias folding ----------------

__global__ void bnprep_k(const float* __restrict__ b1, const float* __restrict__ b2,
                         const float* __restrict__ b3,
                         const float* __restrict__ g1, const float* __restrict__ be1,
                         const float* __restrict__ rm1, const float* __restrict__ rv1,
                         const float* __restrict__ g2, const float* __restrict__ be2,
                         const float* __restrict__ rm2, const float* __restrict__ rv2,
                         float* __restrict__ scsh) {
  int t = threadIdx.x;
  int j = t & 63, l = t >> 6;
  float sc, sh;
  if (l == 0)      { sc = g1[j] * rsqrtf(rv1[j] + EPS); sh = (b1[j] - rm1[j]) * sc + be1[j]; }
  else if (l == 1) { sc = g2[j] * rsqrtf(rv2[j] + EPS); sh = (b2[j] - rm2[j]) * sc + be2[j]; }
  else             { sc = 1.0f;                          sh = b3[j]; }
  scsh[l * 128 + j] = sc;
  scsh[l * 128 + 64 + j] = sh;
}

// ---------------- GEMM: out[r] = dis[r] * (in[r] @ W), fp16 out, fp32/fp16 in --------

#define GT_R 128
#define XT_LD 132

__device__ inline float ld1(const float* p)  { return *p; }
__device__ inline float ld1(const __half* p) { return __half2float(*p); }

template <typename InT>
__global__ __launch_bounds__(256) void gemm_k(const InT* __restrict__ in,
                                              const float* __restrict__ W,
                                              const float* __restrict__ dis,
                                              __half* __restrict__ out, int nrows) {
  __shared__ float ws[64 * 64];
  __shared__ float xt[64 * XT_LD];
  __shared__ float dtile[GT_R];

  const int t    = threadIdx.x;
  const int lane = t & 63;
  const int w    = t >> 6;
  const int row0 = blockIdx.x * GT_R;

  for (int i = t; i < 1024; i += 256)
    ((float4*)ws)[i] = ((const float4*)W)[i];

  if (t < GT_R) {
    int r = row0 + t;
    dtile[t] = (r < nrows) ? dis[r] : 0.f;
  }

#pragma unroll
  for (int j = 0; j < 8; ++j) {
    int Q = w + 4 * j;
    int r = row0 + 4 * Q;
    float4 v;
    v.x = (r + 0 < nrows) ? ld1(&in[(size_t)(r + 0) * D + lane]) : 0.f;
    v.y = (r + 1 < nrows) ? ld1(&in[(size_t)(r + 1) * D + lane]) : 0.f;
    v.z = (r + 2 < nrows) ? ld1(&in[(size_t)(r + 2) * D + lane]) : 0.f;
    v.w = (r + 3 < nrows) ? ld1(&in[(size_t)(r + 3) * D + lane]) : 0.f;
    *(float4*)&xt[lane * XT_LD + 4 * Q] = v;
  }
  __syncthreads();

  const int cq = (t & 15) * 4;
  const int rg = (t >> 4) * 8;
  float acc[8][4] = {};

#pragma unroll 4
  for (int k = 0; k < 64; ++k) {
    float4 b   = *(const float4*)&ws[k * 64 + cq];
    float4 alo = *(const float4*)&xt[k * XT_LD + rg];
    float4 ahi = *(const float4*)&xt[k * XT_LD + rg + 4];
    const float ar[8] = {alo.x, alo.y, alo.z, alo.w, ahi.x, ahi.y, ahi.z, ahi.w};
#pragma unroll
    for (int i = 0; i < 8; ++i) {
      acc[i][0] = fmaf(ar[i], b.x, acc[i][0]);
      acc[i][1] = fmaf(ar[i], b.y, acc[i][1]);
      acc[i][2] = fmaf(ar[i], b.z, acc[i][2]);
      acc[i][3] = fmaf(ar[i], b.w, acc[i][3]);
    }
  }

#pragma unroll
  for (int i = 0; i < 8; ++i) {
    int r = row0 + rg + i;
    if (r < nrows) {
      float dsc = dtile[rg + i];
      union { __half2 h[2]; float2 f; } u;
      u.h[0] = __floats2half2_rn(dsc * acc[i][0], dsc * acc[i][1]);
      u.h[1] = __floats2half2_rn(dsc * acc[i][2], dsc * acc[i][3]);
      *(float2*)&out[(size_t)r * D + cq] = u.f;
    }
  }
}

// ---------------- Aggregation: packed-fp16 accumulate, int4 index loads -------------
// Wave = 1 dst node. 16-lane group g handles edges e+4g..e+4g+3 (one int4 col load,
// group-uniform). Lane loads uint2 = 4 fp16 feats; accumulate with v_pk_add_f16
// (slot chains are length <=1 for deg<=16 -> fp16 adds exact); fp32 combine+reduce.

template <bool RELU, typename OutT>
__global__ __launch_bounds__(256) void agg_k(const __half* __restrict__ h2s,
                                             const int2* __restrict__ rpdeg,
                                             const int* __restrict__ col,
                                             const float* __restrict__ dis,
                                             const float* __restrict__ scsh,
                                             OutT* __restrict__ out, int n) {
  const int lane = threadIdx.x & 63;
  const int node = __builtin_amdgcn_readfirstlane((blockIdx.x * blockDim.x + threadIdx.x) >> 6);
  if (node >= n) return;
  const int g  = lane >> 4;
  const int sl = lane & 15;
  const uint2* __restrict__ h2v = (const uint2*)h2s;   // row = 16 x uint2

  const int2 rd = rpdeg[node];
  const int p0 = rd.x, deg = rd.y;

  float f0 = 0.f, f1 = 0.f, f2 = 0.f, f3 = 0.f;   // self term (fp32, group 0)
  {
    uint2 r = h2v[(size_t)node * 16 + sl];
    float2 x0 = __half22float2(*(const __half2*)&r.x);
    float2 x1 = __half22float2(*(const __half2*)&r.y);
    if (g == 0) { f0 = x0.x; f1 = x0.y; f2 = x1.x; f3 = x1.y; }
  }

  const __half2 zero2 = __floats2half2_rn(0.f, 0.f);
  __half2 A0 = zero2, A1 = zero2, B0 = zero2, B1 = zero2;
  __half2 C0 = zero2, C1 = zero2, D0 = zero2, D1 = zero2;
  const int jb = 4 * g;

  for (int e = 0; e < deg; e += 16) {
    const int4 cc = *(const int4*)&col[p0 + e + jb];   // 4 indices, group-uniform
    uint2 r0 = h2v[(size_t)cc.x * 16 + sl];
    uint2 r1 = h2v[(size_t)cc.y * 16 + sl];
    uint2 r2 = h2v[(size_t)cc.z * 16 + sl];
    uint2 r3 = h2v[(size_t)cc.w * 16 + sl];
    const int j = e + jb;
    const uint2 zz = make_uint2(0u, 0u);
    r0 = (j + 0 < deg) ? r0 : zz;
    r1 = (j + 1 < deg) ? r1 : zz;
    r2 = (j + 2 < deg) ? r2 : zz;
    r3 = (j + 3 < deg) ? r3 : zz;
    A0 = __hadd2(A0, *(const __half2*)&r0.x); A1 = __hadd2(A1, *(const __half2*)&r0.y);
    B0 = __hadd2(B0, *(const __half2*)&r1.x); B1 = __hadd2(B1, *(const __half2*)&r1.y);
    C0 = __hadd2(C0, *(const __half2*)&r2.x); C1 = __hadd2(C1, *(const __half2*)&r2.y);
    D0 = __hadd2(D0, *(const __half2*)&r3.x); D1 = __hadd2(D1, *(const __half2*)&r3.y);
  }

  const float2 a0 = __half22float2(A0), a1 = __half22float2(A1);
  const float2 b0 = __half22float2(B0), b1 = __half22float2(B1);
  const float2 c0 = __half22float2(C0), c1 = __half22float2(C1);
  const float2 d0 = __half22float2(D0), d1 = __half22float2(D1);
  float r0 = f0 + ((a0.x + b0.x) + (c0.x + d0.x));
  float r1 = f1 + ((a0.y + b0.y) + (c0.y + d0.y));
  float r2 = f2 + ((a1.x + b1.x) + (c1.x + d1.x));
  float r3 = f3 + ((a1.y + b1.y) + (c1.y + d1.y));
  // reduce across the 4 groups (lanes sl, sl+16, sl+32, sl+48)
  r0 += __shfl_xor(r0, 16, 64); r1 += __shfl_xor(r1, 16, 64);
  r2 += __shfl_xor(r2, 16, 64); r3 += __shfl_xor(r3, 16, 64);
  r0 += __shfl_xor(r0, 32, 64); r1 += __shfl_xor(r1, 32, 64);
  r2 += __shfl_xor(r2, 32, 64); r3 += __shfl_xor(r3, 32, 64);

  const float di = dis[node];
  const float4 sc = *(const float4*)&scsh[4 * sl];
  const float4 sh = *(const float4*)&scsh[64 + 4 * sl];
  float o0 = fmaf(di * r0, sc.x, sh.x);
  float o1 = fmaf(di * r1, sc.y, sh.y);
  float o2 = fmaf(di * r2, sc.z, sh.z);
  float o3 = fmaf(di * r3, sc.w, sh.w);
  if (RELU) {
    o0 = fmaxf(o0, 0.f); o1 = fmaxf(o1, 0.f);
    o2 = fmaxf(o2, 0.f); o3 = fmaxf(o3, 0.f);
  }
  if (g == 0) {
    if constexpr (sizeof(OutT) == 2) {
      union { __half2 h[2]; uint2 u; } v;
      v.h[0] = __floats2half2_rn(o0, o1);
      v.h[1] = __floats2half2_rn(o2, o3);
      *(uint2*)&out[(size_t)node * D + 4 * sl] = v.u;
    } else {
      *(float4*)&out[(size_t)node * D + 4 * sl] = make_float4(o0, o1, o2, o3);
    }
  }
}

// ---------------- Global mean pool (batch is sorted) ----------------

__global__ __launch_bounds__(256) void pool_k(const float* __restrict__ h,
                                              const int* __restrict__ batch,
                                              float* __restrict__ psum,
                                              float* __restrict__ pcnt, int n) {
  int lane  = threadIdx.x & 63;
  int wid   = __builtin_amdgcn_readfirstlane((blockIdx.x * blockDim.x + threadIdx.x) >> 6);
  int start = wid * 64;
  if (start >= n) return;
  int end = min(start + 64, n);
  int cur = batch[start];
  float sum = 0.f;
  int run = 0;
  for (int i = start; i < end; ++i) {
    int g = batch[i];
    if (g != cur) {
      atomicAdd(&psum[cur * D + lane], sum);
      if (lane == 0) atomicAdd(&pcnt[cur], (float)run);
      sum = 0.f; run = 0; cur = g;
    }
    sum += h[(size_t)i * D + lane];
    run += 1;
  }
  atomicAdd(&psum[cur * D + lane], sum);
  if (lane == 0) atomicAdd(&pcnt[cur], (float)run);
}

__global__ void pooldiv_k(const float* __restrict__ psum, const float* __restrict__ pcnt,
                          float* __restrict__ hg) {
  int t = blockIdx.x * blockDim.x + threadIdx.x;
  if (t < 64 * D) hg[t] = psum[t] / fmaxf(pcnt[t >> 6], 1.0f);
}

// ---------------- launcher ----------------

extern "C" void kernel_launch(void* const* d_in, const int* in_sizes, int n_in,
                              void* d_out, int out_size, void* d_ws, size_t ws_size,
                              hipStream_t stream) {
  const float* x   = (const float*)d_in[0];
  const int*   ei  = (const int*)d_in[1];
  const int*   bat = (const int*)d_in[2];
  const float* W1  = (const float*)d_in[3];
  const float* W2  = (const float*)d_in[4];
  const float* W3  = (const float*)d_in[5];
  const float* b1  = (const float*)d_in[6];
  const float* b2  = (const float*)d_in[7];
  const float* b3  = (const float*)d_in[8];
  const float* g1  = (const float*)d_in[9];
  const float* be1 = (const float*)d_in[10];
  const float* rm1 = (const float*)d_in[11];
  const float* rv1 = (const float*)d_in[12];
  const float* g2  = (const float*)d_in[13];
  const float* be2 = (const float*)d_in[14];
  const float* rm2 = (const float*)d_in[15];
  const float* rv2 = (const float*)d_in[16];

  const int n = in_sizes[0] / D;   // 100000
  const int e = in_sizes[1] / 2;   // 1200000
  const int* src = ei;
  const int* dst = ei + e;
  const int nbk = (n + BK_W - 1) >> BK_SHIFT;   // 196

  char* ws = (char*)d_ws;
  size_t off = 0;
  auto alloc = [&](size_t bytes) -> void* {
    void* p = ws + off;
    off = (off + bytes + 255) & ~(size_t)255;
    return p;
  };
  __half* buf16 = (__half*)alloc((size_t)n * D * 2);        // agg fp16 out (layers 1,2)
  int*    pairs = (int*)alloc((size_t)NBMAX * BK_CAP * 4);  // bucket slabs
  __half* hbuf  = (__half*)alloc((size_t)n * D * 2);        // gemm fp16 out (dis-scaled)
  int2*   rpdeg = (int2*)alloc((size_t)n * 8);
  float*  dis   = (float*)alloc((size_t)n * 4);
  int*    col   = (int*)alloc((size_t)NBMAX * BK_CAP * 4);  // CSR in padded slabs
  float*  scsh  = (float*)alloc(6 * 64 * 4);
  // zero-init cluster: bcnt + psum + pcnt in one contiguous memset
  int*    bcnt  = (int*)alloc(NBMAX * 4);
  float*  psum  = (float*)alloc(64 * D * 4);
  float*  pcnt  = (float*)alloc(64 * 4);
  const size_t zbytes = ((char*)pcnt + 64 * 4) - (char*)bcnt;

  float* hout = (float*)d_out;
  float* hg   = (float*)d_out + (size_t)n * D;

  hipMemsetAsync(bcnt, 0, zbytes, stream);

  bucket_k<<<(e + CHUNK - 1) / CHUNK, 256, 0, stream>>>(src, dst, bcnt, pairs, e, nbk);
  bucket2csr_k<<<nbk, 256, 0, stream>>>(bcnt, pairs, rpdeg, dis, col, n);
  bnprep_k<<<1, 192, 0, stream>>>(b1, b2, b3, g1, be1, rm1, rv1, g2, be2, rm2, rv2, scsh);

  const int gemm_blocks = (n + GT_R - 1) / GT_R;
  const int agg_blocks  = (n * 64 + 255) / 256;

  // layer 1
  gemm_k<float><<<gemm_blocks, 256, 0, stream>>>(x, W1, dis, hbuf, n);
  agg_k<true, __half><<<agg_blocks, 256, 0, stream>>>(hbuf, rpdeg, col, dis, scsh + 0 * 128, buf16, n);
  // layer 2
  gemm_k<__half><<<gemm_blocks, 256, 0, stream>>>(buf16, W2, dis, hbuf, n);
  agg_k<true, __half><<<agg_blocks, 256, 0, stream>>>(hbuf, rpdeg, col, dis, scsh + 1 * 128, buf16, n);
  // layer 3
  gemm_k<__half><<<gemm_blocks, 256, 0, stream>>>(buf16, W3, dis, hbuf, n);
  agg_k<false, float><<<agg_blocks, 256, 0, stream>>>(hbuf, rpdeg, col, dis, scsh + 2 * 128, hout, n);

  // pooling
  const int pool_waves = (n + 63) / 64;
  pool_k<<<(pool_waves * 64 + 255) / 256, 256, 0, stream>>>(hout, bat, psum, pcnt, n);
  pooldiv_k<<<(64 * D + 255) / 256, 256, 0, stream>>>(psum, pcnt, hg);
}

// Round 10
// 350.704 us; speedup vs baseline: 1.0740x; 1.0420x over previous
//
#include <hip/hip_runtime.h>
#include <hip/hip_fp16.h>

#define D 64
#define EPS 1e-5f

// CSR bucketing params: buckets of 512 consecutive dst nodes
#define BK_SHIFT 9
#define BK_W 512
#define NBMAX 256        // supports n up to 131072
#define BK_CAP 8192      // avg padded ~7040/bucket; margin ok
#define CHUNK 8192       // edges per bucket_k block

// ---------------- Phase A: bucketize edges; pack (src<<9 | dst_local) ----------------

__global__ __launch_bounds__(256) void bucket_k(const int* __restrict__ src,
                                                const int* __restrict__ dst,
                                                int* __restrict__ bcnt,
                                                int* __restrict__ pairs,
                                                int e, int nbk) {
  __shared__ int hcnt[NBMAX];
  __shared__ int hbase[NBMAX];
  const int t = threadIdx.x;
  const int e0 = blockIdx.x * CHUNK;
  const int e1 = min(e0 + CHUNK, e);
  for (int i = t; i < nbk; i += 256) hcnt[i] = 0;
  __syncthreads();
  for (int i = e0 + t; i < e1; i += 256)
    atomicAdd(&hcnt[dst[i] >> BK_SHIFT], 1);
  __syncthreads();
  for (int i = t; i < nbk; i += 256) {
    int c = hcnt[i];
    hbase[i] = c ? atomicAdd(&bcnt[i], c) : 0;
    hcnt[i] = 0;   // reuse as cursor
  }
  __syncthreads();
  for (int i = e0 + t; i < e1; i += 256) {
    int s = src[i], d = dst[i];
    int b = d >> BK_SHIFT;
    int r = hbase[b] + atomicAdd(&hcnt[b], 1);
    if (r < BK_CAP) pairs[(size_t)b * BK_CAP + r] = (s << BK_SHIFT) | (d & (BK_W - 1));
  }
}

// ---------------- Fused CSR: hist -> padded scan -> rpdeg/dis -> place -> col --------
// Node segments padded to multiples of 4 ints (so agg can int4-load indices).
// stage pre-zeroed => pad slots hold index 0 (valid row; data zeroed by predicate).

__global__ __launch_bounds__(256) void bucket2csr_k(const int* __restrict__ bcnt,
                                                    const int* __restrict__ pairs,
                                                    int2* __restrict__ rpdeg,
                                                    float* __restrict__ dis,
                                                    int* __restrict__ col, int n) {
  __shared__ int h[BK_W];
  __shared__ int cur[BK_W];
  __shared__ int s1[256], s2[256];
  __shared__ int stage[BK_CAP];
  const int b = blockIdx.x, t = threadIdx.x;
  const int base = b << BK_SHIFT;
  const int slab0 = b * BK_CAP;
  const int m = min(bcnt[b], BK_CAP);

  h[t] = 0; h[t + 256] = 0;
  for (int i = t; i < BK_CAP; i += 256) stage[i] = 0;
  __syncthreads();
  const int* p = pairs + (size_t)b * BK_CAP;
  for (int i = t; i < m; i += 256) atomicAdd(&h[p[i] & (BK_W - 1)], 1);
  __syncthreads();

  const int pc1 = (h[t] + 3) & ~3;         // padded counts (x4 alignment)
  const int pc2 = (h[t + 256] + 3) & ~3;
  s1[t] = pc1; s2[t] = pc2;
  __syncthreads();
  for (int off = 1; off < 256; off <<= 1) {
    int x1 = (t >= off) ? s1[t - off] : 0;
    int x2 = (t >= off) ? s2[t - off] : 0;
    __syncthreads();
    s1[t] += x1; s2[t] += x2;
    __syncthreads();
  }
  const int tot1 = s1[255];
  const int mpad = tot1 + s2[255];
  cur[t]       = s1[t] - pc1;
  cur[t + 256] = tot1 + s2[t] - pc2;
  {
    int n1 = base + t, n2 = base + t + 256;
    if (n1 < n) { rpdeg[n1] = make_int2(slab0 + cur[t], h[t]);
                  dis[n1] = rsqrtf((float)h[t] + 1.0f); }
    if (n2 < n) { rpdeg[n2] = make_int2(slab0 + cur[t + 256], h[t + 256]);
                  dis[n2] = rsqrtf((float)h[t + 256] + 1.0f); }
  }
  __syncthreads();

  for (int i = t; i < m; i += 256) {
    int pk = p[i];
    int r = atomicAdd(&cur[pk & (BK_W - 1)], 1);
    stage[r] = pk >> BK_SHIFT;
  }
  __syncthreads();
  const int mout = min(mpad + 16, BK_CAP);   // +16 zero tail for agg over-read
  for (int i = t; i < mout; i += 256) col[slab0 + i] = stage[i];
}

// ---------------- BN/bias folding ----------------

__global__ void bnprep_k(const float* __restrict__ b1, const float* __restrict__ b2,
                         const float* __restrict__ b3,
                         const float* __restrict__ g1, const float* __restrict__ be1,
                         const float* __restrict__ rm1, const float* __restrict__ rv1,
                         const float* __restrict__ g2, const float* __restrict__ be2,
                         const float* __restrict__ rm2, const float* __restrict__ rv2,
                         float* __restrict__ scsh) {
  int t = threadIdx.x;
  int j = t & 63, l = t >> 6;
  float sc, sh;
  if (l == 0)      { sc = g1[j] * rsqrtf(rv1[j] + EPS); sh = (b1[j] - rm1[j]) * sc + be1[j]; }
  else if (l == 1) { sc = g2[j] * rsqrtf(rv2[j] + EPS); sh = (b2[j] - rm2[j]) * sc + be2[j]; }
  else             { sc = 1.0f;                          sh = b3[j]; }
  scsh[l * 128 + j] = sc;
  scsh[l * 128 + 64 + j] = sh;
}

// ---------------- GEMM: out[r] = dis[r] * (in[r] @ W), fp16 out, fp32/fp16 in --------

#define GT_R 128
#define XT_LD 132

__device__ inline float ld1(const float* p)  { return *p; }
__device__ inline float ld1(const __half* p) { return __half2float(*p); }

template <typename InT>
__global__ __launch_bounds__(256) void gemm_k(const InT* __restrict__ in,
                                              const float* __restrict__ W,
                                              const float* __restrict__ dis,
                                              __half* __restrict__ out, int nrows) {
  __shared__ float ws[64 * 64];
  __shared__ float xt[64 * XT_LD];
  __shared__ float dtile[GT_R];

  const int t    = threadIdx.x;
  const int lane = t & 63;
  const int w    = t >> 6;
  const int row0 = blockIdx.x * GT_R;

  for (int i = t; i < 1024; i += 256)
    ((float4*)ws)[i] = ((const float4*)W)[i];

  if (t < GT_R) {
    int r = row0 + t;
    dtile[t] = (r < nrows) ? dis[r] : 0.f;
  }

#pragma unroll
  for (int j = 0; j < 8; ++j) {
    int Q = w + 4 * j;
    int r = row0 + 4 * Q;
    float4 v;
    v.x = (r + 0 < nrows) ? ld1(&in[(size_t)(r + 0) * D + lane]) : 0.f;
    v.y = (r + 1 < nrows) ? ld1(&in[(size_t)(r + 1) * D + lane]) : 0.f;
    v.z = (r + 2 < nrows) ? ld1(&in[(size_t)(r + 2) * D + lane]) : 0.f;
    v.w = (r + 3 < nrows) ? ld1(&in[(size_t)(r + 3) * D + lane]) : 0.f;
    *(float4*)&xt[lane * XT_LD + 4 * Q] = v;
  }
  __syncthreads();

  const int cq = (t & 15) * 4;
  const int rg = (t >> 4) * 8;
  float acc[8][4] = {};

#pragma unroll 4
  for (int k = 0; k < 64; ++k) {
    float4 b   = *(const float4*)&ws[k * 64 + cq];
    float4 alo = *(const float4*)&xt[k * XT_LD + rg];
    float4 ahi = *(const float4*)&xt[k * XT_LD + rg + 4];
    const float ar[8] = {alo.x, alo.y, alo.z, alo.w, ahi.x, ahi.y, ahi.z, ahi.w};
#pragma unroll
    for (int i = 0; i < 8; ++i) {
      acc[i][0] = fmaf(ar[i], b.x, acc[i][0]);
      acc[i][1] = fmaf(ar[i], b.y, acc[i][1]);
      acc[i][2] = fmaf(ar[i], b.z, acc[i][2]);
      acc[i][3] = fmaf(ar[i], b.w, acc[i][3]);
    }
  }

#pragma unroll
  for (int i = 0; i < 8; ++i) {
    int r = row0 + rg + i;
    if (r < nrows) {
      float dsc = dtile[rg + i];
      union { __half2 h[2]; float2 f; } u;
      u.h[0] = __floats2half2_rn(dsc * acc[i][0], dsc * acc[i][1]);
      u.h[1] = __floats2half2_rn(dsc * acc[i][2], dsc * acc[i][3]);
      *(float2*)&out[(size_t)r * D + cq] = u.f;
    }
  }
}

// ---------------- Aggregation: 2 nodes per wave (sequential, interleaved chains) ----
// Wave w owns nodes 2w and 2w+1, full 64-lane layout per node (16-lane group g
// handles edges 4g..4g+3 of a 16-batch; lane loads uint2 = 4 fp16 feats).
// Both nodes' rpdeg (one int4), col int4s, self rows, and first-batch gathers
// issue together -> ~2x memory lines in flight vs 1 node/wave.

template <bool RELU, typename OutT>
__global__ __launch_bounds__(256) void agg_k(const __half* __restrict__ h2s,
                                             const int2* __restrict__ rpdeg,
                                             const int* __restrict__ col,
                                             const float* __restrict__ dis,
                                             const float* __restrict__ scsh,
                                             OutT* __restrict__ out, int n) {
  const int lane = threadIdx.x & 63;
  const int wv   = (blockIdx.x * blockDim.x + threadIdx.x) >> 6;
  const int n0   = __builtin_amdgcn_readfirstlane(wv * 2);
  if (n0 >= n) return;
  const bool v1 = (n0 + 1 < n);
  const int n1  = v1 ? n0 + 1 : n0;
  const int g  = lane >> 4;
  const int sl = lane & 15;
  const int jb = 4 * g;
  const uint2* __restrict__ h2v = (const uint2*)h2s;   // row = 16 x uint2

  // paired rpdeg: one 16B load (n0 even -> aligned)
  const int4 rdp = *(const int4*)&rpdeg[n0];
  const int p0 = rdp.x, deg0 = rdp.y, p1 = rdp.z, deg1 = rdp.w;

  // self rows + first-batch indices for both nodes: all issued up front
  const uint2 self0 = h2v[(size_t)n0 * 16 + sl];
  const uint2 self1 = h2v[(size_t)n1 * 16 + sl];
  const int4 cc0 = *(const int4*)&col[p0 + jb];
  const int4 cc1 = *(const int4*)&col[p1 + jb];

  const __half2 zero2 = __floats2half2_rn(0.f, 0.f);
  const uint2 zz = make_uint2(0u, 0u);

  __half2 A0 = zero2, A1 = zero2, B0 = zero2, B1 = zero2;
  __half2 C0 = zero2, C1 = zero2, D0 = zero2, D1 = zero2;   // node0
  __half2 E0 = zero2, E1 = zero2, F0 = zero2, F1 = zero2;
  __half2 G0 = zero2, G1 = zero2, H0 = zero2, H1 = zero2;   // node1

  {  // first batch, node0 (unconditional: pad/tail slots hold index 0, predicated out)
    uint2 r0 = h2v[(size_t)cc0.x * 16 + sl];
    uint2 r1 = h2v[(size_t)cc0.y * 16 + sl];
    uint2 r2 = h2v[(size_t)cc0.z * 16 + sl];
    uint2 r3 = h2v[(size_t)cc0.w * 16 + sl];
    // first batch, node1
    uint2 q0 = h2v[(size_t)cc1.x * 16 + sl];
    uint2 q1 = h2v[(size_t)cc1.y * 16 + sl];
    uint2 q2 = h2v[(size_t)cc1.z * 16 + sl];
    uint2 q3 = h2v[(size_t)cc1.w * 16 + sl];
    r0 = (jb + 0 < deg0) ? r0 : zz;  r1 = (jb + 1 < deg0) ? r1 : zz;
    r2 = (jb + 2 < deg0) ? r2 : zz;  r3 = (jb + 3 < deg0) ? r3 : zz;
    q0 = (jb + 0 < deg1) ? q0 : zz;  q1 = (jb + 1 < deg1) ? q1 : zz;
    q2 = (jb + 2 < deg1) ? q2 : zz;  q3 = (jb + 3 < deg1) ? q3 : zz;
    A0 = __hadd2(A0, *(const __half2*)&r0.x); A1 = __hadd2(A1, *(const __half2*)&r0.y);
    B0 = __hadd2(B0, *(const __half2*)&r1.x); B1 = __hadd2(B1, *(const __half2*)&r1.y);
    C0 = __hadd2(C0, *(const __half2*)&r2.x); C1 = __hadd2(C1, *(const __half2*)&r2.y);
    D0 = __hadd2(D0, *(const __half2*)&r3.x); D1 = __hadd2(D1, *(const __half2*)&r3.y);
    E0 = __hadd2(E0, *(const __half2*)&q0.x); E1 = __hadd2(E1, *(const __half2*)&q0.y);
    F0 = __hadd2(F0, *(const __half2*)&q1.x); F1 = __hadd2(F1, *(const __half2*)&q1.y);
    G0 = __hadd2(G0, *(const __half2*)&q2.x); G1 = __hadd2(G1, *(const __half2*)&q2.y);
    H0 = __hadd2(H0, *(const __half2*)&q3.x); H1 = __hadd2(H1, *(const __half2*)&q3.y);
  }

  // tails (deg > 16), per node
  for (int e = 16; e < deg0; e += 16) {
    const int4 cc = *(const int4*)&col[p0 + e + jb];
    uint2 r0 = h2v[(size_t)cc.x * 16 + sl];
    uint2 r1 = h2v[(size_t)cc.y * 16 + sl];
    uint2 r2 = h2v[(size_t)cc.z * 16 + sl];
    uint2 r3 = h2v[(size_t)cc.w * 16 + sl];
    const int j = e + jb;
    r0 = (j + 0 < deg0) ? r0 : zz;  r1 = (j + 1 < deg0) ? r1 : zz;
    r2 = (j + 2 < deg0) ? r2 : zz;  r3 = (j + 3 < deg0) ? r3 : zz;
    A0 = __hadd2(A0, *(const __half2*)&r0.x); A1 = __hadd2(A1, *(const __half2*)&r0.y);
    B0 = __hadd2(B0, *(const __half2*)&r1.x); B1 = __hadd2(B1, *(const __half2*)&r1.y);
    C0 = __hadd2(C0, *(const __half2*)&r2.x); C1 = __hadd2(C1, *(const __half2*)&r2.y);
    D0 = __hadd2(D0, *(const __half2*)&r3.x); D1 = __hadd2(D1, *(const __half2*)&r3.y);
  }
  for (int e = 16; e < deg1; e += 16) {
    const int4 cc = *(const int4*)&col[p1 + e + jb];
    uint2 q0 = h2v[(size_t)cc.x * 16 + sl];
    uint2 q1 = h2v[(size_t)cc.y * 16 + sl];
    uint2 q2 = h2v[(size_t)cc.z * 16 + sl];
    uint2 q3 = h2v[(size_t)cc.w * 16 + sl];
    const int j = e + jb;
    q0 = (j + 0 < deg1) ? q0 : zz;  q1 = (j + 1 < deg1) ? q1 : zz;
    q2 = (j + 2 < deg1) ? q2 : zz;  q3 = (j + 3 < deg1) ? q3 : zz;
    E0 = __hadd2(E0, *(const __half2*)&q0.x); E1 = __hadd2(E1, *(const __half2*)&q0.y);
    F0 = __hadd2(F0, *(const __half2*)&q1.x); F1 = __hadd2(F1, *(const __half2*)&q1.y);
    G0 = __hadd2(G0, *(const __half2*)&q2.x); G1 = __hadd2(G1, *(const __half2*)&q2.y);
    H0 = __hadd2(H0, *(const __half2*)&q3.x); H1 = __hadd2(H1, *(const __half2*)&q3.y);
  }

  const float di0 = dis[n0];
  const float di1 = dis[n1];
  const float4 sc = *(const float4*)&scsh[4 * sl];
  const float4 sh = *(const float4*)&scsh[64 + 4 * sl];

  // ---- node0 combine/reduce/store ----
  {
    const float2 a0 = __half22float2(A0), a1 = __half22float2(A1);
    const float2 b0 = __half22float2(B0), b1 = __half22float2(B1);
    const float2 c0 = __half22float2(C0), c1 = __half22float2(C1);
    const float2 d0 = __half22float2(D0), d1 = __half22float2(D1);
    float2 s0f = __half22float2(*(const __half2*)&self0.x);
    float2 s1f = __half22float2(*(const __half2*)&self0.y);
    float r0 = ((a0.x + b0.x) + (c0.x + d0.x)) + (g == 0 ? s0f.x : 0.f);
    float r1 = ((a0.y + b0.y) + (c0.y + d0.y)) + (g == 0 ? s0f.y : 0.f);
    float r2 = ((a1.x + b1.x) + (c1.x + d1.x)) + (g == 0 ? s1f.x : 0.f);
    float r3 = ((a1.y + b1.y) + (c1.y + d1.y)) + (g == 0 ? s1f.y : 0.f);
    r0 += __shfl_xor(r0, 16, 64); r1 += __shfl_xor(r1, 16, 64);
    r2 += __shfl_xor(r2, 16, 64); r3 += __shfl_xor(r3, 16, 64);
    r0 += __shfl_xor(r0, 32, 64); r1 += __shfl_xor(r1, 32, 64);
    r2 += __shfl_xor(r2, 32, 64); r3 += __shfl_xor(r3, 32, 64);
    float o0 = fmaf(di0 * r0, sc.x, sh.x);
    float o1 = fmaf(di0 * r1, sc.y, sh.y);
    float o2 = fmaf(di0 * r2, sc.z, sh.z);
    float o3 = fmaf(di0 * r3, sc.w, sh.w);
    if (RELU) {
      o0 = fmaxf(o0, 0.f); o1 = fmaxf(o1, 0.f);
      o2 = fmaxf(o2, 0.f); o3 = fmaxf(o3, 0.f);
    }
    if (g == 0) {
      if constexpr (sizeof(OutT) == 2) {
        union { __half2 h[2]; uint2 u; } v;
        v.h[0] = __floats2half2_rn(o0, o1);
        v.h[1] = __floats2half2_rn(o2, o3);
        *(uint2*)&out[(size_t)n0 * D + 4 * sl] = v.u;
      } else {
        *(float4*)&out[(size_t)n0 * D + 4 * sl] = make_float4(o0, o1, o2, o3);
      }
    }
  }
  // ---- node1 combine/reduce/store ----
  {
    const float2 a0 = __half22float2(E0), a1 = __half22float2(E1);
    const float2 b0 = __half22float2(F0), b1 = __half22float2(F1);
    const float2 c0 = __half22float2(G0), c1 = __half22float2(G1);
    const float2 d0 = __half22float2(H0), d1 = __half22float2(H1);
    float2 s0f = __half22float2(*(const __half2*)&self1.x);
    float2 s1f = __half22float2(*(const __half2*)&self1.y);
    float r0 = ((a0.x + b0.x) + (c0.x + d0.x)) + (g == 0 ? s0f.x : 0.f);
    float r1 = ((a0.y + b0.y) + (c0.y + d0.y)) + (g == 0 ? s0f.y : 0.f);
    float r2 = ((a1.x + b1.x) + (c1.x + d1.x)) + (g == 0 ? s1f.x : 0.f);
    float r3 = ((a1.y + b1.y) + (c1.y + d1.y)) + (g == 0 ? s1f.y : 0.f);
    r0 += __shfl_xor(r0, 16, 64); r1 += __shfl_xor(r1, 16, 64);
    r2 += __shfl_xor(r2, 16, 64); r3 += __shfl_xor(r3, 16, 64);
    r0 += __shfl_xor(r0, 32, 64); r1 += __shfl_xor(r1, 32, 64);
    r2 += __shfl_xor(r2, 32, 64); r3 += __shfl_xor(r3, 32, 64);
    float o0 = fmaf(di1 * r0, sc.x, sh.x);
    float o1 = fmaf(di1 * r1, sc.y, sh.y);
    float o2 = fmaf(di1 * r2, sc.z, sh.z);
    float o3 = fmaf(di1 * r3, sc.w, sh.w);
    if (RELU) {
      o0 = fmaxf(o0, 0.f); o1 = fmaxf(o1, 0.f);
      o2 = fmaxf(o2, 0.f); o3 = fmaxf(o3, 0.f);
    }
    if (g == 0 && v1) {
      if constexpr (sizeof(OutT) == 2) {
        union { __half2 h[2]; uint2 u; } v;
        v.h[0] = __floats2half2_rn(o0, o1);
        v.h[1] = __floats2half2_rn(o2, o3);
        *(uint2*)&out[(size_t)n1 * D + 4 * sl] = v.u;
      } else {
        *(float4*)&out[(size_t)n1 * D + 4 * sl] = make_float4(o0, o1, o2, o3);
      }
    }
  }
}

// ---------------- Global mean pool (batch is sorted) ----------------

__global__ __launch_bounds__(256) void pool_k(const float* __restrict__ h,
                                              const int* __restrict__ batch,
                                              float* __restrict__ psum,
                                              float* __restrict__ pcnt, int n) {
  int lane  = threadIdx.x & 63;
  int wid   = __builtin_amdgcn_readfirstlane((blockIdx.x * blockDim.x + threadIdx.x) >> 6);
  int start = wid * 64;
  if (start >= n) return;
  int end = min(start + 64, n);
  int cur = batch[start];
  float sum = 0.f;
  int run = 0;
  for (int i = start; i < end; ++i) {
    int g = batch[i];
    if (g != cur) {
      atomicAdd(&psum[cur * D + lane], sum);
      if (lane == 0) atomicAdd(&pcnt[cur], (float)run);
      sum = 0.f; run = 0; cur = g;
    }
    sum += h[(size_t)i * D + lane];
    run += 1;
  }
  atomicAdd(&psum[cur * D + lane], sum);
  if (lane == 0) atomicAdd(&pcnt[cur], (float)run);
}

__global__ void pooldiv_k(const float* __restrict__ psum, const float* __restrict__ pcnt,
                          float* __restrict__ hg) {
  int t = blockIdx.x * blockDim.x + threadIdx.x;
  if (t < 64 * D) hg[t] = psum[t] / fmaxf(pcnt[t >> 6], 1.0f);
}

// ---------------- launcher ----------------

extern "C" void kernel_launch(void* const* d_in, const int* in_sizes, int n_in,
                              void* d_out, int out_size, void* d_ws, size_t ws_size,
                              hipStream_t stream) {
  const float* x   = (const float*)d_in[0];
  const int*   ei  = (const int*)d_in[1];
  const int*   bat = (const int*)d_in[2];
  const float* W1  = (const float*)d_in[3];
  const float* W2  = (const float*)d_in[4];
  const float* W3  = (const float*)d_in[5];
  const float* b1  = (const float*)d_in[6];
  const float* b2  = (const float*)d_in[7];
  const float* b3  = (const float*)d_in[8];
  const float* g1  = (const float*)d_in[9];
  const float* be1 = (const float*)d_in[10];
  const float* rm1 = (const float*)d_in[11];
  const float* rv1 = (const float*)d_in[12];
  const float* g2  = (const float*)d_in[13];
  const float* be2 = (const float*)d_in[14];
  const float* rm2 = (const float*)d_in[15];
  const float* rv2 = (const float*)d_in[16];

  const int n = in_sizes[0] / D;   // 100000
  const int e = in_sizes[1] / 2;   // 1200000
  const int* src = ei;
  const int* dst = ei + e;
  const int nbk = (n + BK_W - 1) >> BK_SHIFT;   // 196

  char* ws = (char*)d_ws;
  size_t off = 0;
  auto alloc = [&](size_t bytes) -> void* {
    void* p = ws + off;
    off = (off + bytes + 255) & ~(size_t)255;
    return p;
  };
  __half* buf16 = (__half*)alloc((size_t)n * D * 2);        // agg fp16 out (layers 1,2)
  int*    pairs = (int*)alloc((size_t)NBMAX * BK_CAP * 4);  // bucket slabs
  __half* hbuf  = (__half*)alloc((size_t)n * D * 2);        // gemm fp16 out (dis-scaled)
  int2*   rpdeg = (int2*)alloc((size_t)(n + 1) * 8);
  float*  dis   = (float*)alloc((size_t)n * 4);
  int*    col   = (int*)alloc((size_t)NBMAX * BK_CAP * 4);  // CSR in padded slabs
  float*  scsh  = (float*)alloc(6 * 64 * 4);
  // zero-init cluster: bcnt + psum + pcnt in one contiguous memset
  int*    bcnt  = (int*)alloc(NBMAX * 4);
  float*  psum  = (float*)alloc(64 * D * 4);
  float*  pcnt  = (float*)alloc(64 * 4);
  const size_t zbytes = ((char*)pcnt + 64 * 4) - (char*)bcnt;

  float* hout = (float*)d_out;
  float* hg   = (float*)d_out + (size_t)n * D;

  hipMemsetAsync(bcnt, 0, zbytes, stream);

  bucket_k<<<(e + CHUNK - 1) / CHUNK, 256, 0, stream>>>(src, dst, bcnt, pairs, e, nbk);
  bucket2csr_k<<<nbk, 256, 0, stream>>>(bcnt, pairs, rpdeg, dis, col, n);
  bnprep_k<<<1, 192, 0, stream>>>(b1, b2, b3, g1, be1, rm1, rv1, g2, be2, rm2, rv2, scsh);

  const int gemm_blocks = (n + GT_R - 1) / GT_R;
  const int agg_waves   = (n + 1) / 2;
  const int agg_blocks  = (agg_waves * 64 + 255) / 256;

  // layer 1
  gemm_k<float><<<gemm_blocks, 256, 0, stream>>>(x, W1, dis, hbuf, n);
  agg_k<true, __half><<<agg_blocks, 256, 0, stream>>>(hbuf, rpdeg, col, dis, scsh + 0 * 128, buf16, n);
  // layer 2
  gemm_k<__half><<<gemm_blocks, 256, 0, stream>>>(buf16, W2, dis, hbuf, n);
  agg_k<true, __half><<<agg_blocks, 256, 0, stream>>>(hbuf, rpdeg, col, dis, scsh + 1 * 128, buf16, n);
  // layer 3
  gemm_k<__half><<<gemm_blocks, 256, 0, stream>>>(buf16, W3, dis, hbuf, n);
  agg_k<false, float><<<agg_blocks, 256, 0, stream>>>(hbuf, rpdeg, col, dis, scsh + 2 * 128, hout, n);

  // pooling
  const int pool_waves = (n + 63) / 64;
  pool_k<<<(pool_waves * 64 + 255) / 256, 256, 0, stream>>>(hout, bat, psum, pcnt, n);
  pooldiv_k<<<(64 * D + 255) / 256, 256, 0, stream>>>(psum, pcnt, hg);
}